// Round 9
// baseline (53.864 us; speedup 1.0000x reference)
//
#include <hip/hip_runtime.h>
#include <hip/hip_bf16.h>
#include <hip/hip_fp8.h>
#include <stdint.h>

typedef __attribute__((ext_vector_type(4))) float f32x4;
typedef __attribute__((ext_vector_type(2))) unsigned int u32x2;
typedef __attribute__((ext_vector_type(4))) unsigned int u32x4;

#define N_ROWS 8192
#define DIM 256            // K (bytes per row in fp8)
#define BM 256             // i-rows per block (8 waves x 32 rows, t=2)
#define BJ 128             // j-cols staged per LDS tile
#define JCHUNKS 16
#define JCHUNK (N_ROWS / JCHUNKS)   // 512 -> 4 tiles of 128 per block

// r' = r_normalized * sqrt(10*log2(e)); dot(r'_i,r'_j) = 10*log2(e)*sim,
// so exp(10*sim) = exp2(dot).
#define SCL 3.79828252f

// ---- Kernel A: normalize rows -> fp8 e4m3 r'; zero den & out ---------------
__global__ void k_norm(const float* __restrict__ reps,
                       unsigned char* __restrict__ rq,
                       float* __restrict__ den,
                       float* __restrict__ out) {
  const int w = threadIdx.x >> 6, lane = threadIdx.x & 63;
  const int row = blockIdx.x * 4 + w;
  const float4 v = reinterpret_cast<const float4*>(reps + row * DIM)[lane];
  float ss = v.x * v.x + v.y * v.y + v.z * v.z + v.w * v.w;
#pragma unroll
  for (int m = 1; m < 64; m <<= 1) ss += __shfl_xor(ss, m);
  const float scale = SCL / fmaxf(sqrtf(ss), 1e-12f);
  // OCP e4m3 (gfx950 native); |r'| <= 3.8 << 448, no saturation concerns
  const uint32_t b0 = __hip_fp8_e4m3(v.x * scale).__x;
  const uint32_t b1 = __hip_fp8_e4m3(v.y * scale).__x;
  const uint32_t b2 = __hip_fp8_e4m3(v.z * scale).__x;
  const uint32_t b3 = __hip_fp8_e4m3(v.w * scale).__x;
  *reinterpret_cast<uint32_t*>(rq + (size_t)row * DIM + lane * 4) =
      b0 | (b1 << 8) | (b2 << 16) | (b3 << 24);
  if (threadIdx.x < 4) den[blockIdx.x * 4 + threadIdx.x] = 0.0f;
  if (blockIdx.x == 0 && threadIdx.x == 0) out[0] = 0.0f;
}

// ---- Kernel B: fp8 fused sim + exp + mask + row-sum, dbuf LDS --------------
// grid (32, 16), 512 threads (8 waves, t=2 each -> BM=256). 64 KB LDS dbuf
// -> 2 blocks/CU -> 16 waves/CU = 4 waves/SIMD (2x R8's occupancy, which was
// the round-9 hypothesis: k_sim is dependency-stall-bound at 2 waves/SIMD).
// Inner loop, fragment maps, swizzle identical to R8 (verified absmax 0.0).
__global__ __launch_bounds__(512, 4) void k_sim(
    const unsigned char* __restrict__ rq,
    const int* __restrict__ lab,
    float* __restrict__ den) {
  __shared__ unsigned char Bs[2][BJ * DIM];  // 2 x 32 KB, 16B-chunk XOR-swizzled

  const int tid = threadIdx.x;
  const int w = tid >> 6, lane = tid & 63;
  const int l15 = lane & 15, lq = lane >> 4;
  const int ibase = blockIdx.x * BM + w * 32;   // this wave's 32 rows
  const int jc0 = blockIdx.y * JCHUNK;

  // A fragments: 2 i-subtiles x 8 k-chunks (8B each) = 32 VGPR.
  // MFMA (kc2,half) consumes row bytes [kc2*64 + lq*16 + half*8, +8);
  // identical convention for A and B so any k-permutation cancels.
  long a[2][8];
#pragma unroll
  for (int t = 0; t < 2; ++t) {
    const unsigned char* ap =
        rq + (size_t)(ibase + t * 16 + l15) * DIM + lq * 16;
#pragma unroll
    for (int kc2 = 0; kc2 < 4; ++kc2) {
      const u32x4 v = *reinterpret_cast<const u32x4*>(ap + kc2 * 64);
      a[t][2 * kc2]     = __builtin_bit_cast(long, (u32x2){v.x, v.y});
      a[t][2 * kc2 + 1] = __builtin_bit_cast(long, (u32x2){v.z, v.w});
    }
  }
  int labi[2][4];
#pragma unroll
  for (int t = 0; t < 2; ++t)
#pragma unroll
    for (int r = 0; r < 4; ++r)
      labi[t][r] = lab[ibase + t * 16 + lq * 4 + r];

  f32x4 dsum[2] = {{0.f, 0.f, 0.f, 0.f}, {0.f, 0.f, 0.f, 0.f}};

  const int lrow0 = w * 16;  // each wave stages 16 rows (4 instr x 4 rows)

  // prologue: stage tile 0 into buf 0
#pragma unroll
  for (int q = 0; q < 4; ++q) {
    const int lrow = lrow0 + q * 4 + lq;
    const int ch = l15 ^ (lrow & 7);  // 16B-chunk swizzle
    const unsigned char* g = rq + (size_t)(jc0 + lrow) * DIM + ch * 16;
    unsigned char* l = Bs[0] + (lrow0 + q * 4) * DIM;  // +lane*16 implicit
    __builtin_amdgcn_global_load_lds(
        (const __attribute__((address_space(1))) uint32_t*)g,
        (__attribute__((address_space(3))) uint32_t*)l, 16, 0, 0);
  }

  for (int jt = 0; jt < JCHUNK / BJ; ++jt) {
    const int cur = jt & 1;
    const int j0 = jc0 + jt * BJ;

    __syncthreads();  // buf[cur] staged; prior reads of buf[cur^1] done

    // issue staging of NEXT tile into the other buffer (hidden under compute)
    if (jt < JCHUNK / BJ - 1) {
      const int jn = j0 + BJ;
#pragma unroll
      for (int q = 0; q < 4; ++q) {
        const int lrow = lrow0 + q * 4 + lq;
        const int ch = l15 ^ (lrow & 7);
        const unsigned char* g = rq + (size_t)(jn + lrow) * DIM + ch * 16;
        unsigned char* l = Bs[cur ^ 1] + (lrow0 + q * 4) * DIM;
        __builtin_amdgcn_global_load_lds(
            (const __attribute__((address_space(1))) uint32_t*)g,
            (__attribute__((address_space(3))) uint32_t*)l, 16, 0, 0);
      }
    }

    int labj[8];
#pragma unroll
    for (int s = 0; s < 8; ++s) labj[s] = lab[j0 + s * 16 + l15];

    const unsigned char* Bb = Bs[cur];
#pragma unroll
    for (int s = 0; s < 8; ++s) {
      f32x4 acc0 = {0.f, 0.f, 0.f, 0.f};
      f32x4 acc1 = {0.f, 0.f, 0.f, 0.f};
      const int brow = s * 16 + l15;
      const unsigned char* bp = Bb + brow * DIM;
      const int sw = brow & 7;
#pragma unroll
      for (int kc2 = 0; kc2 < 4; ++kc2) {
        const int ch = (kc2 * 4 + lq) ^ sw;
        const u32x4 bv = *reinterpret_cast<const u32x4*>(bp + ch * 16);
        const long blo = __builtin_bit_cast(long, (u32x2){bv.x, bv.y});
        const long bhi = __builtin_bit_cast(long, (u32x2){bv.z, bv.w});
        acc0 = __builtin_amdgcn_mfma_f32_16x16x32_fp8_fp8(a[0][2 * kc2], blo, acc0, 0, 0, 0);
        acc1 = __builtin_amdgcn_mfma_f32_16x16x32_fp8_fp8(a[1][2 * kc2], blo, acc1, 0, 0, 0);
        acc0 = __builtin_amdgcn_mfma_f32_16x16x32_fp8_fp8(a[0][2 * kc2 + 1], bhi, acc0, 0, 0, 0);
        acc1 = __builtin_amdgcn_mfma_f32_16x16x32_fp8_fp8(a[1][2 * kc2 + 1], bhi, acc1, 0, 0, 0);
      }
#pragma unroll
      for (int r = 0; r < 4; ++r) {
        float e0 = __builtin_amdgcn_exp2f(acc0[r]);
        float e1 = __builtin_amdgcn_exp2f(acc1[r]);
        dsum[0][r] += (labi[0][r] == labj[s]) ? 1.0f : e0;
        dsum[1][r] += (labi[1][r] == labj[s]) ? 1.0f : e1;
      }
    }
  }

  // sum over the 16 lanes sharing each output row, then one atomic per row
#pragma unroll
  for (int t = 0; t < 2; ++t)
#pragma unroll
    for (int r = 0; r < 4; ++r) {
      float v = dsum[t][r];
      v += __shfl_xor(v, 1);
      v += __shfl_xor(v, 2);
      v += __shfl_xor(v, 4);
      v += __shfl_xor(v, 8);
      if (l15 == 0) atomicAdd(&den[ibase + t * 16 + lq * 4 + r], v);
    }
}

// ---- Kernel C: loss = mean(log(den + 1 + eps)) -----------------------------
__global__ void k_loss(const float* __restrict__ den, float* __restrict__ out) {
  const int idx = blockIdx.x * 256 + threadIdx.x;
  float v = logf(den[idx] + 1.0f + 1e-8f);  // +1 = num_diag
#pragma unroll
  for (int m = 1; m < 64; m <<= 1) v += __shfl_xor(v, m);
  __shared__ float sred[4];
  if ((threadIdx.x & 63) == 0) sred[threadIdx.x >> 6] = v;
  __syncthreads();
  if (threadIdx.x == 0)
    atomicAdd(out, (sred[0] + sred[1] + sred[2] + sred[3]) * (1.0f / (float)N_ROWS));
}

extern "C" void kernel_launch(void* const* d_in, const int* in_sizes, int n_in,
                              void* d_out, int out_size, void* d_ws, size_t ws_size,
                              hipStream_t stream) {
  const float* reps = (const float*)d_in[0];
  const int* lab = (const int*)d_in[1];
  float* out = (float*)d_out;
  unsigned char* rq = (unsigned char*)d_ws;                        // 2 MB fp8 r'
  float* den = (float*)((char*)d_ws + (size_t)N_ROWS * DIM);       // 32 KB

  k_norm<<<N_ROWS / 4, 256, 0, stream>>>(reps, rq, den, out);
  k_sim<<<dim3(N_ROWS / BM, JCHUNKS), 512, 0, stream>>>(rq, lab, den);
  k_loss<<<N_ROWS / 256, 256, 0, stream>>>(den, out);
}

// Round 10
// 35.353 us; speedup vs baseline: 1.5236x; 1.5236x over previous
//
#include <hip/hip_runtime.h>
#include <hip/hip_bf16.h>
#include <hip/hip_fp8.h>
#include <stdint.h>

typedef __attribute__((ext_vector_type(4))) float f32x4;
typedef __attribute__((ext_vector_type(4))) unsigned int u32x4;
typedef __attribute__((ext_vector_type(8))) int i32x8;

#define N_ROWS 8192
#define DIM 256            // K (bytes per row in fp8)
#define BM 128             // i-rows per block (4 waves x 32 rows, t=2)
#define BJ 128             // j-cols staged per LDS tile
#define JCHUNKS 8
#define JCHUNK (N_ROWS / JCHUNKS)   // 1024 -> 8 tiles of 128 per block

// r' = r_normalized * sqrt(10*log2(e)); dot(r'_i,r'_j) = 10*log2(e)*sim,
// so exp(10*sim) = exp2(dot).
#define SCL 3.79828252f

// E8M0 unit scale in all 4 bytes: 127 -> 2^0 = 1.0
#define UNIT_SCALE 0x7F7F7F7F

// ---- Kernel A: normalize rows -> fp8 e4m3 r'; zero den & out ---------------
__global__ void k_norm(const float* __restrict__ reps,
                       unsigned char* __restrict__ rq,
                       float* __restrict__ den,
                       float* __restrict__ out) {
  const int w = threadIdx.x >> 6, lane = threadIdx.x & 63;
  const int row = blockIdx.x * 4 + w;
  const float4 v = reinterpret_cast<const float4*>(reps + row * DIM)[lane];
  float ss = v.x * v.x + v.y * v.y + v.z * v.z + v.w * v.w;
#pragma unroll
  for (int m = 1; m < 64; m <<= 1) ss += __shfl_xor(ss, m);
  const float scale = SCL / fmaxf(sqrtf(ss), 1e-12f);
  // OCP e4m3 (gfx950 native); |r'| <= 3.8 << 448, no saturation concerns
  const uint32_t b0 = __hip_fp8_e4m3(v.x * scale).__x;
  const uint32_t b1 = __hip_fp8_e4m3(v.y * scale).__x;
  const uint32_t b2 = __hip_fp8_e4m3(v.z * scale).__x;
  const uint32_t b3 = __hip_fp8_e4m3(v.w * scale).__x;
  *reinterpret_cast<uint32_t*>(rq + (size_t)row * DIM + lane * 4) =
      b0 | (b1 << 8) | (b2 << 16) | (b3 << 24);
  if (threadIdx.x < 4) den[blockIdx.x * 4 + threadIdx.x] = 0.0f;
  if (blockIdx.x == 0 && threadIdx.x == 0) out[0] = 0.0f;
}

// ---- Kernel B: MX-fp8 (K=128) fused sim + exp + mask + row-sum -------------
// R8's exact config (grid (64,8), 256 thr, 64KB LDS dbuf, 2 blocks/CU) and
// staging/swizzle/epilogue; only the inner compute changes: 16x16x128
// mfma_scale with unit E8M0 scales runs at 2x the fp8-16x16x32 rate, halving
// the MFMA-pipe floor (16.6 -> 7.3us) at identical LDS traffic and ~same
// register footprint (~100 arch, inside the proven no-spill envelope).
__global__ __launch_bounds__(256, 2) void k_sim(
    const unsigned char* __restrict__ rq,
    const int* __restrict__ lab,
    float* __restrict__ den) {
  __shared__ unsigned char Bs[2][BJ * DIM];  // 2 x 32 KB, 16B-chunk XOR-swizzled

  const int tid = threadIdx.x;
  const int w = tid >> 6, lane = tid & 63;
  const int l15 = lane & 15, lq = lane >> 4;
  const int ibase = blockIdx.x * BM + w * 32;   // this wave's 32 rows
  const int jc0 = blockIdx.y * JCHUNK;

  // A fragments: 2 i-subtiles x 2 K-windows (32B each) = 32 VGPR.
  // Fragment map (same for A and B so any k-permutation cancels):
  // window kc covers k-bytes [kc*128 + lq*32, +32) of the row.
  i32x8 a[2][2];
#pragma unroll
  for (int t = 0; t < 2; ++t) {
    const unsigned char* ap = rq + (size_t)(ibase + t * 16 + l15) * DIM + lq * 32;
#pragma unroll
    for (int kc = 0; kc < 2; ++kc) {
      const u32x4 v0 = *reinterpret_cast<const u32x4*>(ap + kc * 128);
      const u32x4 v1 = *reinterpret_cast<const u32x4*>(ap + kc * 128 + 16);
      a[t][kc] = (i32x8){(int)v0.x, (int)v0.y, (int)v0.z, (int)v0.w,
                         (int)v1.x, (int)v1.y, (int)v1.z, (int)v1.w};
    }
  }
  int labi[2][4];
#pragma unroll
  for (int t = 0; t < 2; ++t)
#pragma unroll
    for (int r = 0; r < 4; ++r)
      labi[t][r] = lab[ibase + t * 16 + lq * 4 + r];

  f32x4 dsum[2] = {{0.f, 0.f, 0.f, 0.f}, {0.f, 0.f, 0.f, 0.f}};

  const int lrow0 = w * 32;  // each wave stages 32 rows (8 instr x 4 rows)

  // prologue: stage tile 0 into buf 0
#pragma unroll
  for (int q = 0; q < 8; ++q) {
    const int lrow = lrow0 + q * 4 + lq;
    const int ch = l15 ^ (lrow & 7);  // 16B-chunk swizzle
    const unsigned char* g = rq + (size_t)(jc0 + lrow) * DIM + ch * 16;
    unsigned char* l = Bs[0] + (lrow0 + q * 4) * DIM;  // +lane*16 implicit
    __builtin_amdgcn_global_load_lds(
        (const __attribute__((address_space(1))) uint32_t*)g,
        (__attribute__((address_space(3))) uint32_t*)l, 16, 0, 0);
  }

  for (int jt = 0; jt < JCHUNK / BJ; ++jt) {
    const int cur = jt & 1;
    const int j0 = jc0 + jt * BJ;

    __syncthreads();  // buf[cur] staged; prior reads of buf[cur^1] done

    // issue staging of NEXT tile into the other buffer (hidden under compute)
    if (jt < JCHUNK / BJ - 1) {
      const int jn = j0 + BJ;
#pragma unroll
      for (int q = 0; q < 8; ++q) {
        const int lrow = lrow0 + q * 4 + lq;
        const int ch = l15 ^ (lrow & 7);
        const unsigned char* g = rq + (size_t)(jn + lrow) * DIM + ch * 16;
        unsigned char* l = Bs[cur ^ 1] + (lrow0 + q * 4) * DIM;
        __builtin_amdgcn_global_load_lds(
            (const __attribute__((address_space(1))) uint32_t*)g,
            (__attribute__((address_space(3))) uint32_t*)l, 16, 0, 0);
      }
    }

    int labj[8];
#pragma unroll
    for (int s = 0; s < 8; ++s) labj[s] = lab[j0 + s * 16 + l15];

    const unsigned char* Bb = Bs[cur];
#pragma unroll
    for (int s = 0; s < 8; ++s) {
      f32x4 acc0 = {0.f, 0.f, 0.f, 0.f};
      f32x4 acc1 = {0.f, 0.f, 0.f, 0.f};
      const int brow = s * 16 + l15;
      const unsigned char* bp = Bb + brow * DIM;
      const int sw = brow & 7;
#pragma unroll
      for (int kc = 0; kc < 2; ++kc) {
        const int base = kc * 8 + lq * 2;
        const u32x4 b0 = *reinterpret_cast<const u32x4*>(bp + (base ^ sw) * 16);
        const u32x4 b1 = *reinterpret_cast<const u32x4*>(bp + ((base + 1) ^ sw) * 16);
        const i32x8 bb = (i32x8){(int)b0.x, (int)b0.y, (int)b0.z, (int)b0.w,
                                 (int)b1.x, (int)b1.y, (int)b1.z, (int)b1.w};
        acc0 = __builtin_amdgcn_mfma_scale_f32_16x16x128_f8f6f4(
            a[0][kc], bb, acc0, 0, 0, 0, UNIT_SCALE, 0, UNIT_SCALE);
        acc1 = __builtin_amdgcn_mfma_scale_f32_16x16x128_f8f6f4(
            a[1][kc], bb, acc1, 0, 0, 0, UNIT_SCALE, 0, UNIT_SCALE);
      }
#pragma unroll
      for (int r = 0; r < 4; ++r) {
        float e0 = __builtin_amdgcn_exp2f(acc0[r]);
        float e1 = __builtin_amdgcn_exp2f(acc1[r]);
        dsum[0][r] += (labi[0][r] == labj[s]) ? 1.0f : e0;
        dsum[1][r] += (labi[1][r] == labj[s]) ? 1.0f : e1;
      }
    }
  }

  // sum over the 16 lanes sharing each output row, then one atomic per row
#pragma unroll
  for (int t = 0; t < 2; ++t)
#pragma unroll
    for (int r = 0; r < 4; ++r) {
      float v = dsum[t][r];
      v += __shfl_xor(v, 1);
      v += __shfl_xor(v, 2);
      v += __shfl_xor(v, 4);
      v += __shfl_xor(v, 8);
      if (l15 == 0) atomicAdd(&den[ibase + t * 16 + lq * 4 + r], v);
    }
}

// ---- Kernel C: loss = mean(log(den + 1 + eps)) -----------------------------
__global__ void k_loss(const float* __restrict__ den, float* __restrict__ out) {
  const int idx = blockIdx.x * 256 + threadIdx.x;
  float v = logf(den[idx] + 1.0f + 1e-8f);  // +1 = num_diag
#pragma unroll
  for (int m = 1; m < 64; m <<= 1) v += __shfl_xor(v, m);
  __shared__ float sred[4];
  if ((threadIdx.x & 63) == 0) sred[threadIdx.x >> 6] = v;
  __syncthreads();
  if (threadIdx.x == 0)
    atomicAdd(out, (sred[0] + sred[1] + sred[2] + sred[3]) * (1.0f / (float)N_ROWS));
}

extern "C" void kernel_launch(void* const* d_in, const int* in_sizes, int n_in,
                              void* d_out, int out_size, void* d_ws, size_t ws_size,
                              hipStream_t stream) {
  const float* reps = (const float*)d_in[0];
  const int* lab = (const int*)d_in[1];
  float* out = (float*)d_out;
  unsigned char* rq = (unsigned char*)d_ws;                        // 2 MB fp8 r'
  float* den = (float*)((char*)d_ws + (size_t)N_ROWS * DIM);       // 32 KB

  k_norm<<<N_ROWS / 4, 256, 0, stream>>>(reps, rq, den, out);
  k_sim<<<dim3(N_ROWS / BM, JCHUNKS), 256, 0, stream>>>(rq, lab, den);
  k_loss<<<N_ROWS / 256, 256, 0, stream>>>(den, out);
}